// Round 3
// baseline (2412.198 us; speedup 1.0000x reference)
//
#include <hip/hip_runtime.h>
#include <hip/hip_bf16.h>

// Sparse 3D conv block (4x 27-tap convs, N=64), float32 in/out.
// Round 3: software-pipelined K-loop (register prefetch of next tap's gather +
//          weights across the MFMA) + conflict-free staging-write mapping.
//   - split-bf16 emulated f32 (hi*hi + hi*lo + lo*hi), verified absmax 0.016
//   - staging chunk map e = c*32 + q*8 -> LDS write word-offsets 4(r+q) mod 32
//     uniform over banks (was 4-way imbalanced)
//   - prefetch tap k+1 into VGPRs right after staging-writes of tap k, so the
//     ~500cyc gather latency overlaps barrier+MFMA of tap k

#define N 64
#define TAPS 27
#define MT 64
#define PITCH 72   // bf16 elems per LDS row (144 B)

typedef unsigned short u16;
typedef __attribute__((ext_vector_type(8))) short short8;
typedef __attribute__((ext_vector_type(4))) float floatx4;

__device__ __forceinline__ float bf2f(u16 v) {
    union { unsigned u; float f; } c;
    c.u = ((unsigned)v) << 16;
    return c.f;
}
__device__ __forceinline__ u16 f2bf(float f) {
    __hip_bfloat16 h = __float2bfloat16(f);  // RNE
    u16 r;
    __builtin_memcpy(&r, &h, 2);
    return r;
}
__device__ __forceinline__ void split2(float x, u16& hi, u16& lo) {
    hi = f2bf(x);
    lo = f2bf(x - bf2f(hi));
}

// feats f32 [P][64] -> hl bf16 [P][128] (row = hi[0:64] || lo[64:128])
__global__ void split_feats(const float* __restrict__ x, u16* __restrict__ hl, int n) {
    int i = blockIdx.x * 256 + threadIdx.x;
    if (i >= n) return;
    int p = i >> 6, c = i & 63;
    u16 h, l;
    split2(x[i], h, l);
    hl[(size_t)p * 128 + c] = h;
    hl[(size_t)p * 128 + 64 + c] = l;
}

// W f32 [27][64][64] (k,i,j) -> Wt bf16 [27][64][128] (k, j, i_hi||i_lo)
__global__ void transpose_w(const float* __restrict__ W, u16* __restrict__ Wt) {
    const float* src = W + blockIdx.x * (N * N);
    u16* dst = Wt + blockIdx.x * (N * 128);
    int t = threadIdx.x;
#pragma unroll
    for (int m = 0; m < 16; ++m) {
        int e = t + m * 256;
        int i = e >> 6;
        int j = e & 63;
        u16 h, l;
        split2(src[e], h, l);
        dst[j * 128 + i] = h;
        dst[j * 128 + 64 + i] = l;
    }
}

// MODE: 0/2 = relu -> hl out; 1 = FiLM -> hl out; 3 = relu + residual -> f32 out
template <int MODE>
__global__ __launch_bounds__(256) void conv_k(
    const u16* __restrict__ Xhl, const u16* __restrict__ Wt,
    const float* __restrict__ bias, const int* __restrict__ nbr,
    const float* __restrict__ cond, const float* __restrict__ resid,
    u16* __restrict__ out_hl, float* __restrict__ out_f32, int P) {
    __shared__ u16 Ah[MT * PITCH];
    __shared__ u16 Al[MT * PITCH];
    __shared__ u16 Bh[N * PITCH];
    __shared__ u16 Bl[N * PITCH];
    __shared__ int Ns[MT * TAPS];

    const int tid = threadIdx.x;
    const int pbase = blockIdx.x * MT;

    for (int e = tid; e < MT * TAPS; e += 256) {
        int r = e / TAPS;
        int p = pbase + r;
        Ns[e] = (p < P) ? nbr[p * TAPS + (e - r * TAPS)] : -1;
    }

    const int wave = tid >> 6;
    const int lane = tid & 63;
    const int lm = lane & 15;   // row/col within 16x16 tile
    const int lb = lane >> 4;   // k sub-block 0..3

    const int r = tid >> 2;     // staging row 0..63
    const int q = tid & 3;      // 16B sub-chunk within each 64B group

    floatx4 acc[4];
#pragma unroll
    for (int i = 0; i < 4; ++i) acc[i] = (floatx4){0.f, 0.f, 0.f, 0.f};

    __syncthreads();  // Ns visible before first prefetch

    // ---- prologue: prefetch tap 0 into registers
    uint4 pa[4], pb[4];
    {
        int idx = Ns[r * TAPS + 0];
        const u16* wsrc = Wt + r * 128;
#pragma unroll
        for (int c = 0; c < 4; ++c) {
            int e = c * 32 + q * 8;
            pa[c] = make_uint4(0u, 0u, 0u, 0u);
            if (idx >= 0)
                pa[c] = *reinterpret_cast<const uint4*>(Xhl + (size_t)idx * 128 + e);
            pb[c] = *reinterpret_cast<const uint4*>(wsrc + e);
        }
    }

    for (int k = 0; k < TAPS; ++k) {
        __syncthreads();  // prior iteration's MFMA frag-reads complete

        // ---- stage tap k from prefetch registers
        // word offsets 36r + 16c + 4q -> per-instruction 4(r+q) mod 32: uniform
#pragma unroll
        for (int c = 0; c < 4; ++c) {
            int e = c * 32 + q * 8;
            if (c < 2) {
                *reinterpret_cast<uint4*>(&Ah[r * PITCH + e]) = pa[c];
                *reinterpret_cast<uint4*>(&Bh[r * PITCH + e]) = pb[c];
            } else {
                *reinterpret_cast<uint4*>(&Al[r * PITCH + e - 64]) = pa[c];
                *reinterpret_cast<uint4*>(&Bl[r * PITCH + e - 64]) = pb[c];
            }
        }

        // ---- issue prefetch of tap k+1 (latency overlaps barrier + MFMA)
        if (k + 1 < TAPS) {
            int idx = Ns[r * TAPS + k + 1];
            const u16* wsrc = Wt + (size_t)(k + 1) * (N * 128) + r * 128;
#pragma unroll
            for (int c = 0; c < 4; ++c) {
                int e = c * 32 + q * 8;
                uint4 av = make_uint4(0u, 0u, 0u, 0u);
                if (idx >= 0)
                    av = *reinterpret_cast<const uint4*>(Xhl + (size_t)idx * 128 + e);
                pa[c] = av;
                pb[c] = *reinterpret_cast<const uint4*>(wsrc + e);
            }
        }

        __syncthreads();  // staged data visible

        // ---- MFMA: wave handles rows [wave*16, wave*16+16) x all 64 cols
        short8 ah[2], al[2];
#pragma unroll
        for (int kc = 0; kc < 2; ++kc) {
            int off = (wave * 16 + lm) * PITCH + kc * 32 + lb * 8;
            ah[kc] = *reinterpret_cast<const short8*>(&Ah[off]);
            al[kc] = *reinterpret_cast<const short8*>(&Al[off]);
        }
#pragma unroll
        for (int nt = 0; nt < 4; ++nt) {
#pragma unroll
            for (int kc = 0; kc < 2; ++kc) {
                int off = (nt * 16 + lm) * PITCH + kc * 32 + lb * 8;
                short8 bh = *reinterpret_cast<const short8*>(&Bh[off]);
                short8 bl = *reinterpret_cast<const short8*>(&Bl[off]);
                acc[nt] = __builtin_amdgcn_mfma_f32_16x16x32_bf16(ah[kc], bh, acc[nt], 0, 0, 0);
                acc[nt] = __builtin_amdgcn_mfma_f32_16x16x32_bf16(ah[kc], bl, acc[nt], 0, 0, 0);
                acc[nt] = __builtin_amdgcn_mfma_f32_16x16x32_bf16(al[kc], bh, acc[nt], 0, 0, 0);
            }
        }
    }

    // ---- epilogue: D[row=lb*4+v][col=lm] per 16x16 tile
    const int prow = pbase + wave * 16 + lb * 4;
#pragma unroll
    for (int nt = 0; nt < 4; ++nt) {
        int j = nt * 16 + lm;
        float bj = bias[j];
#pragma unroll
        for (int v = 0; v < 4; ++v) {
            int p = prow + v;
            if (p < P) {
                float o = acc[nt][v] + bj;
                if (MODE == 0 || MODE == 2) o = fmaxf(o, 0.f);
                if (MODE == 1) {
                    float be = cond[(size_t)p * (2 * N) + j];
                    float ga = cond[(size_t)p * (2 * N) + N + j];
                    o = o * be + ga;
                }
                if (MODE == 3) {
                    o = fmaxf(o, 0.f) + resid[(size_t)p * N + j];
                    out_f32[(size_t)p * N + j] = o;
                } else {
                    u16 h, l;
                    split2(o, h, l);
                    out_hl[(size_t)p * 128 + j] = h;
                    out_hl[(size_t)p * 128 + 64 + j] = l;
                }
            }
        }
    }
}

extern "C" void kernel_launch(void* const* d_in, const int* in_sizes, int n_in,
                              void* d_out, int out_size, void* d_ws, size_t ws_size,
                              hipStream_t stream) {
    const float* feats = (const float*)d_in[0];
    const float* cond  = (const float*)d_in[1];
    const float* W1a   = (const float*)d_in[2];
    const float* b1a   = (const float*)d_in[3];
    const float* W1b   = (const float*)d_in[4];
    const float* b1b   = (const float*)d_in[5];
    const float* W2a   = (const float*)d_in[6];
    const float* b2a   = (const float*)d_in[7];
    const float* W2b   = (const float*)d_in[8];
    const float* b2b   = (const float*)d_in[9];
    const int* nbr     = (const int*)d_in[10];
    float* out = (float*)d_out;
    u16* out_hl = (u16*)d_out;   // d_out doubles as hl scratch (P*128 bf16 == P*64 f32 bytes)

    const int P = in_sizes[0] / N;

    const size_t wtElems = (size_t)TAPS * N * 128;  // 221184 bf16 per conv
    u16* wt0 = (u16*)d_ws;
    u16* wt1 = wt0 + wtElems;
    u16* wt2 = wt1 + wtElems;
    u16* wt3 = wt2 + wtElems;
    u16* hA  = wt3 + wtElems;    // P*128 bf16 intermediate

    transpose_w<<<TAPS, 256, 0, stream>>>(W1a, wt0);
    transpose_w<<<TAPS, 256, 0, stream>>>(W1b, wt1);
    transpose_w<<<TAPS, 256, 0, stream>>>(W2a, wt2);
    transpose_w<<<TAPS, 256, 0, stream>>>(W2b, wt3);
    split_feats<<<(P * N + 255) / 256, 256, 0, stream>>>(feats, out_hl, P * N);

    const int blocks = (P + MT - 1) / MT;
    conv_k<0><<<blocks, 256, 0, stream>>>(out_hl, wt0, b1a, nbr, nullptr, nullptr, hA, nullptr, P);
    conv_k<1><<<blocks, 256, 0, stream>>>(hA, wt1, b1b, nbr, cond, nullptr, out_hl, nullptr, P);
    conv_k<2><<<blocks, 256, 0, stream>>>(out_hl, wt2, b2a, nbr, nullptr, nullptr, hA, nullptr, P);
    conv_k<3><<<blocks, 256, 0, stream>>>(hA, wt3, b2b, nbr, nullptr, feats, nullptr, out, P);
}

// Round 4
// 1072.489 us; speedup vs baseline: 2.2492x; 2.2492x over previous
//
#include <hip/hip_runtime.h>
#include <hip/hip_bf16.h>

// Sparse 3D conv block (4x 27-tap convs, N=64), float32 in/out.
// Round 4: MT=128 tile, 32x32x16 MFMA, XOR-swizzled pitch-64 LDS, inline staging.
//   - split-bf16 emulated f32 (hi*hi + hi*lo + lo*hi), verified absmax 0.016
//   - NO cross-barrier register arrays (round-3 spill: +350MB scratch writes)
//   - swizzle: granule g (16B) stored at g ^ (row & 7) -> uniform banks on
//     staging writes AND frag reads (8 lanes/bank-group = b128 minimum)
//   - per-row LDS read cost 1.25 -> 0.75 KB (B tile amortized over 128 rows)

#define N 64
#define TAPS 27
#define MT 128

typedef unsigned short u16;
typedef __attribute__((ext_vector_type(8))) short short8;
typedef __attribute__((ext_vector_type(16))) float floatx16;

__device__ __forceinline__ float bf2f(u16 v) {
    union { unsigned u; float f; } c;
    c.u = ((unsigned)v) << 16;
    return c.f;
}
__device__ __forceinline__ u16 f2bf(float f) {
    __hip_bfloat16 h = __float2bfloat16(f);  // RNE
    u16 r;
    __builtin_memcpy(&r, &h, 2);
    return r;
}
__device__ __forceinline__ void split2(float x, u16& hi, u16& lo) {
    hi = f2bf(x);
    lo = f2bf(x - bf2f(hi));
}

// feats f32 [P][64] -> hl bf16 [P][128] (row = hi[0:64] || lo[64:128])
__global__ void split_feats(const float* __restrict__ x, u16* __restrict__ hl, int n) {
    int i = blockIdx.x * 256 + threadIdx.x;
    if (i >= n) return;
    int p = i >> 6, c = i & 63;
    u16 h, l;
    split2(x[i], h, l);
    hl[(size_t)p * 128 + c] = h;
    hl[(size_t)p * 128 + 64 + c] = l;
}

// W f32 [27][64][64] (k,i,j) -> Wt bf16 [27][64][128] (k, j, i_hi||i_lo)
__global__ void transpose_w(const float* __restrict__ W, u16* __restrict__ Wt) {
    const float* src = W + blockIdx.x * (N * N);
    u16* dst = Wt + blockIdx.x * (N * 128);
    int t = threadIdx.x;
#pragma unroll
    for (int m = 0; m < 16; ++m) {
        int e = t + m * 256;
        int i = e >> 6;
        int j = e & 63;
        u16 h, l;
        split2(src[e], h, l);
        dst[j * 128 + i] = h;
        dst[j * 128 + 64 + i] = l;
    }
}

// MODE: 0/2 = relu -> hl out; 1 = FiLM -> hl out; 3 = relu + residual -> f32 out
template <int MODE>
__global__ __launch_bounds__(256, 3) void conv_k(
    const u16* __restrict__ Xhl, const u16* __restrict__ Wt,
    const float* __restrict__ bias, const int* __restrict__ nbr,
    const float* __restrict__ cond, const float* __restrict__ resid,
    u16* __restrict__ out_hl, float* __restrict__ out_f32, int P) {
    __shared__ u16 Ah[MT * 64];   // 16 KB, rows of 8 swizzled 16B granules
    __shared__ u16 Al[MT * 64];   // 16 KB
    __shared__ u16 Bh[N * 64];    //  8 KB
    __shared__ u16 Bl[N * 64];    //  8 KB

    const int tid = threadIdx.x;
    const int pbase = blockIdx.x * MT;

    // staging roles
    const int ar = tid >> 1;      // A row 0..127
    const int ahalf = tid & 1;    // which 4 granules of the row
    const int br = tid >> 2;      // B row 0..63
    const int bq = tid & 3;

    // compute roles: wave w -> rows [w*32, w*32+32) x 64 cols (2 n-tiles)
    const int w = tid >> 6;
    const int lane = tid & 63;
    const int cn = lane & 31;     // m-row / n-col within 32x32 tile
    const int kh = lane >> 5;     // K half (8-elem group)

    floatx16 acc[2];
#pragma unroll
    for (int nt = 0; nt < 2; ++nt)
#pragma unroll
        for (int i = 0; i < 16; ++i) acc[nt][i] = 0.f;

    const int prA = pbase + ar;
    const long nbrbase = (long)prA * TAPS;
    int idx = (prA < P) ? nbr[nbrbase] : -1;

    const u16* wrow0 = Wt + (size_t)br * 128;

    for (int k = 0; k < TAPS; ++k) {
        if (k) __syncthreads();  // previous tap's frag reads complete

        // ---- stage A: 8 granules of the gathered hl row (zero if missing)
        {
            const u16* xrow = Xhl + (size_t)idx * 128;
#pragma unroll
            for (int c = 0; c < 4; ++c) {
                int g = 4 * ahalf + c;
                int gs = (g ^ (ar & 7)) * 8;
                uint4 vh = make_uint4(0u, 0u, 0u, 0u);
                uint4 vl = make_uint4(0u, 0u, 0u, 0u);
                if (idx >= 0) {
                    vh = *reinterpret_cast<const uint4*>(xrow + g * 8);
                    vl = *reinterpret_cast<const uint4*>(xrow + 64 + g * 8);
                }
                *reinterpret_cast<uint4*>(&Ah[ar * 64 + gs]) = vh;
                *reinterpret_cast<uint4*>(&Al[ar * 64 + gs]) = vl;
            }
        }
        // ---- stage B: 4 granules of Wt[k]
        {
            const u16* wrow = wrow0 + (size_t)k * (N * 128);
#pragma unroll
            for (int jg = 0; jg < 2; ++jg) {
                int g = bq + 4 * jg;
                int gs = (g ^ (br & 7)) * 8;
                *reinterpret_cast<uint4*>(&Bh[br * 64 + gs]) =
                    *reinterpret_cast<const uint4*>(wrow + g * 8);
                *reinterpret_cast<uint4*>(&Bl[br * 64 + gs]) =
                    *reinterpret_cast<const uint4*>(wrow + 64 + g * 8);
            }
        }
        // prefetch next tap's neighbor index (single scalar, cheap)
        idx = (k + 1 < TAPS && prA < P) ? nbr[nbrbase + k + 1] : -1;

        __syncthreads();  // staged data visible

        // ---- MFMA: 4 K-chunks of 16, 2 n-tiles, 3 emulation products
        const int rowA = w * 32 + cn;
#pragma unroll
        for (int kc = 0; kc < 4; ++kc) {
            int g = 2 * kc + kh;
            int offA = rowA * 64 + ((g ^ (rowA & 7)) * 8);
            short8 a_h = *reinterpret_cast<const short8*>(&Ah[offA]);
            short8 a_l = *reinterpret_cast<const short8*>(&Al[offA]);
#pragma unroll
            for (int nt = 0; nt < 2; ++nt) {
                int j = nt * 32 + cn;
                int offB = j * 64 + ((g ^ (j & 7)) * 8);
                short8 b_h = *reinterpret_cast<const short8*>(&Bh[offB]);
                short8 b_l = *reinterpret_cast<const short8*>(&Bl[offB]);
                acc[nt] = __builtin_amdgcn_mfma_f32_32x32x16_bf16(a_h, b_h, acc[nt], 0, 0, 0);
                acc[nt] = __builtin_amdgcn_mfma_f32_32x32x16_bf16(a_h, b_l, acc[nt], 0, 0, 0);
                acc[nt] = __builtin_amdgcn_mfma_f32_32x32x16_bf16(a_l, b_h, acc[nt], 0, 0, 0);
            }
        }
    }

    // ---- epilogue: 32x32 C/D layout col=lane&31, row=(reg&3)+8*(reg>>2)+4*kh
#pragma unroll
    for (int nt = 0; nt < 2; ++nt) {
        int j = nt * 32 + cn;
        float bj = bias[j];
#pragma unroll
        for (int reg = 0; reg < 16; ++reg) {
            int row = (reg & 3) + 8 * (reg >> 2) + 4 * kh;
            int p = pbase + w * 32 + row;
            if (p < P) {
                float o = acc[nt][reg] + bj;
                if (MODE == 0 || MODE == 2) o = fmaxf(o, 0.f);
                if (MODE == 1) {
                    float be = cond[(size_t)p * (2 * N) + j];
                    float ga = cond[(size_t)p * (2 * N) + N + j];
                    o = o * be + ga;
                }
                if (MODE == 3) {
                    o = fmaxf(o, 0.f) + resid[(size_t)p * N + j];
                    out_f32[(size_t)p * N + j] = o;
                } else {
                    u16 h, l;
                    split2(o, h, l);
                    out_hl[(size_t)p * 128 + j] = h;
                    out_hl[(size_t)p * 128 + 64 + j] = l;
                }
            }
        }
    }
}

extern "C" void kernel_launch(void* const* d_in, const int* in_sizes, int n_in,
                              void* d_out, int out_size, void* d_ws, size_t ws_size,
                              hipStream_t stream) {
    const float* feats = (const float*)d_in[0];
    const float* cond  = (const float*)d_in[1];
    const float* W1a   = (const float*)d_in[2];
    const float* b1a   = (const float*)d_in[3];
    const float* W1b   = (const float*)d_in[4];
    const float* b1b   = (const float*)d_in[5];
    const float* W2a   = (const float*)d_in[6];
    const float* b2a   = (const float*)d_in[7];
    const float* W2b   = (const float*)d_in[8];
    const float* b2b   = (const float*)d_in[9];
    const int* nbr     = (const int*)d_in[10];
    float* out = (float*)d_out;
    u16* out_hl = (u16*)d_out;   // d_out doubles as hl scratch (P*128 bf16 == P*64 f32 bytes)

    const int P = in_sizes[0] / N;

    const size_t wtElems = (size_t)TAPS * N * 128;  // 221184 bf16 per conv
    u16* wt0 = (u16*)d_ws;
    u16* wt1 = wt0 + wtElems;
    u16* wt2 = wt1 + wtElems;
    u16* wt3 = wt2 + wtElems;
    u16* hA  = wt3 + wtElems;    // P*128 bf16 intermediate

    transpose_w<<<TAPS, 256, 0, stream>>>(W1a, wt0);
    transpose_w<<<TAPS, 256, 0, stream>>>(W1b, wt1);
    transpose_w<<<TAPS, 256, 0, stream>>>(W2a, wt2);
    transpose_w<<<TAPS, 256, 0, stream>>>(W2b, wt3);
    split_feats<<<(P * N + 255) / 256, 256, 0, stream>>>(feats, out_hl, P * N);

    const int blocks = (P + MT - 1) / MT;
    conv_k<0><<<blocks, 256, 0, stream>>>(out_hl, wt0, b1a, nbr, nullptr, nullptr, hA, nullptr, P);
    conv_k<1><<<blocks, 256, 0, stream>>>(hA, wt1, b1b, nbr, cond, nullptr, out_hl, nullptr, P);
    conv_k<2><<<blocks, 256, 0, stream>>>(out_hl, wt2, b2a, nbr, nullptr, nullptr, hA, nullptr, P);
    conv_k<3><<<blocks, 256, 0, stream>>>(hA, wt3, b2b, nbr, nullptr, feats, nullptr, out, P);
}